// Round 6
// baseline (118.789 us; speedup 1.0000x reference)
//
#include <hip/hip_runtime.h>
#include <hip/hip_bf16.h>
#include <math.h>

#define EPS 1e-8f
#define BB 32
#define SS 64
#define HH 200
#define LL 20
#define KST 232   // bf16 LDS row stride
#define SST 68    // S-tile LDS row stride (floats)
#define MHS 200   // mean/max LDS row stride (floats)

typedef short bf16x8 __attribute__((ext_vector_type(8)));
typedef float f32x4 __attribute__((ext_vector_type(4)));

__device__ inline float bf2f(short u) {
    union { unsigned int i; float f; } v;
    v.i = ((unsigned int)(unsigned short)u) << 16;
    return v.f;
}

// ONE kernel, grid 1792 x 512 (256 groups of 7: 2 type-A + 5 type-C). No workspace.
// r6 = r5 math verbatim; scheduling only: phase-2 k-unroll x4 with batched LDS reads,
// t>>5 thread remap (8-wave phase-2), software-pipelined staging loops.
//
// Type A LDS (floats, 19392 = 77.6 KB -> 2 blocks/CU):
//   [0,1856)       AT 16xKST bf16      \ overlay PB 48xKST bf16 [0,5568)
//   [1856,9280)    BT 64xKST bf16      /
//   [9280,10368)   S_L 16xSST f32      \ overlay WB 32xKST bf16 [9280,12992)
//   [10368,10448)  nrmA(16) nrmB(64)   /
//   [12992,16192)  meanL 16x200 f32
//   [16192,19392)  maxL  16x200 f32
// Type C LDS: AT 64xKST [0,7424) | BT [7424,14848) | cmL [14848,15104)
//             nA [15104,15168) | nB [15168,15232)
__global__ __launch_bounds__(512, 4) void fused_all_kernel(
        const float* __restrict__ conp, const float* __restrict__ conh,
        const float* __restrict__ w1, const float* __restrict__ w2,
        const float* __restrict__ w3, const float* __restrict__ w4,
        const float* __restrict__ w5, const float* __restrict__ w6,
        const float* __restrict__ w7, const float* __restrict__ w8,
        float* __restrict__ out) {
    __shared__ __align__(16) float smem[19392];
    int t = threadIdx.x;

    int grp = blockIdx.x / 7;
    int rem = blockIdx.x % 7;

    if (rem < 2) {
        // ================================ type A (16 self-rows)
        __hip_bfloat16* AT = (__hip_bfloat16*)smem;
        __hip_bfloat16* BT = (__hip_bfloat16*)(smem + 1856);
        float* S_L  = smem + 9280;
        float* nrmA = smem + 10368;
        float* nrmB = smem + 10384;
        __hip_bfloat16* PB = (__hip_bfloat16*)smem;            // phase 3: 48xKST
        __hip_bfloat16* WB = (__hip_bfloat16*)(smem + 9280);   // phase 3: 32xKST
        float* meanL = smem + 12992;
        float* maxL  = smem + 16192;

        int blk = grp * 2 + rem;       // 0..511
        int qh = blk & 3;              // 16-row quarter of self side
        int sdb = blk >> 2;
        int b = sdb & 31, sd = sdb >> 5;
        int dir = sd & 1, side = sd >> 1;
        const float* selfb = side ? conh : conp;
        const float* oppb  = side ? conp : conh;
        int fidx = dir ? 0 : (SS - 1);
        const float* fvr = oppb + (b * SS + fidx) * (2 * HH) + dir * HH;

        int arow = t >> 5, ack = t & 31;   // 16 rows x 32 lanes; ack<25 active
        bool act = (ack < 25);

        // ---- phase 1: stage 16 self rows (regs kept) + fvr prefetch
        float xr[8], yv0[8];
        if (act) {
            const float* xp = selfb + (b * SS + qh * 16 + arow) * (2 * HH) + dir * HH + ack * 8;
            *(float4*)&xr[0] = *(const float4*)xp; *(float4*)&xr[4] = *(const float4*)(xp + 4);
            *(float4*)&yv0[0] = *(const float4*)(fvr + ack * 8);
            *(float4*)&yv0[4] = *(const float4*)(fvr + ack * 8 + 4);
            __align__(16) __hip_bfloat16 r8[8];
#pragma unroll
            for (int i = 0; i < 8; ++i) r8[i] = __float2bfloat16(xr[i]);
            *(bf16x8*)&AT[arow * KST + ack * 8] = *(bf16x8*)r8;
        }
        {
            __align__(16) __hip_bfloat16 z8[8];
#pragma unroll
            for (int i = 0; i < 8; ++i) z8[i] = __float2bfloat16(0.f);
            // pads: AT rows 0-15 ck 25-27 (48) + BT rows 0-63 ck 25-27 (192)
            if (t < 240) {
                if (t < 48) { int row = t / 3, ckp = 25 + t % 3;
                    *(bf16x8*)&AT[row * KST + ckp * 8] = *(bf16x8*)z8;
                } else { int e2 = t - 48; int row = e2 / 3, ckp = 25 + e2 % 3;
                    *(bf16x8*)&BT[row * KST + ckp * 8] = *(bf16x8*)z8;
                }
            }
        }
        // ---- BT staging: 1600 items, 4-slot pipelined (loads first, then convert)
        {
            float qld[4][8];
#pragma unroll
            for (int r = 0; r < 4; ++r) {
                int e = t + 512 * r;
                if (e < 1600) {
                    int rw = e / 25, ck = e % 25;
                    const float* xp = oppb + (b * SS + rw) * (2 * HH) + dir * HH + ck * 8;
                    *(float4*)&qld[r][0] = *(const float4*)xp;
                    *(float4*)&qld[r][4] = *(const float4*)(xp + 4);
                }
            }
#pragma unroll
            for (int r = 0; r < 4; ++r) {
                int e = t + 512 * r;
                if (e < 1600) {
                    int rw = e / 25, ck = e % 25;
                    __align__(16) __hip_bfloat16 r8[8];
#pragma unroll
                    for (int i = 0; i < 8; ++i) r8[i] = __float2bfloat16(qld[r][i]);
                    *(bf16x8*)&BT[rw * KST + ck * 8] = *(bf16x8*)r8;
                }
            }
        }
        __syncthreads();   // B1

        int wv_ = __builtin_amdgcn_readfirstlane(t >> 6);
        int lane = t & 63;
        int q = lane >> 4, c = lane & 15;

        // ---- MFMA: waves 0-3 raw S-tiles; waves 4-7 norm diagonals
        if (wv_ < 4) {
            int ct = wv_;
            f32x4 acc = (f32x4){0.f, 0.f, 0.f, 0.f};
            for (int ks = 0; ks < 7; ++ks) {
                int kb = ks * 32 + q * 8;
                bf16x8 af  = *(const bf16x8*)&AT[c * KST + kb];
                bf16x8 bf_ = *(const bf16x8*)&BT[(ct * 16 + c) * KST + kb];
                acc = __builtin_amdgcn_mfma_f32_16x16x32_bf16(af, bf_, acc, 0, 0, 0);
            }
            int col = ct * 16 + c;
#pragma unroll
            for (int r = 0; r < 4; ++r) S_L[(q * 4 + r) * SST + col] = acc[r];   // raw dot
        } else {
            int dt = wv_ - 4;
            f32x4 accB = (f32x4){0.f, 0.f, 0.f, 0.f};
            for (int ks = 0; ks < 7; ++ks) {
                int kb = ks * 32 + q * 8;
                bf16x8 bf_ = *(const bf16x8*)&BT[(dt * 16 + c) * KST + kb];
                accB = __builtin_amdgcn_mfma_f32_16x16x32_bf16(bf_, bf_, accB, 0, 0, 0);
            }
            if ((c >> 2) == q) nrmB[dt * 16 + c] = accB[c & 3];
            if (dt == 0) {   // wave 4 also does the 16-row A diagonal
                f32x4 accA = (f32x4){0.f, 0.f, 0.f, 0.f};
                for (int ks = 0; ks < 7; ++ks) {
                    int kb = ks * 32 + q * 8;
                    bf16x8 af = *(const bf16x8*)&AT[c * KST + kb];
                    accA = __builtin_amdgcn_mfma_f32_16x16x32_bf16(af, af, accA, 0, 0, 0);
                }
                if ((c >> 2) == q) nrmA[c] = accA[c & 3];
            }
        }
        __syncthreads();   // B2

        // ---- normalize S in place (1024 elems, 2/thread)
        for (int e = t; e < 1024; e += 512) {
            int r_ = e >> 6, cc = e & 63;
            float ns = sqrtf(nrmA[r_]), no = sqrtf(nrmB[cc]);
            S_L[r_ * SST + cc] = S_L[r_ * SST + cc] / fmaxf(ns * no, EPS);
        }
        __syncthreads();   // B3

        // ---- prefetch all three w rows for phase 3 (latency hides under phase 2)
        float wf0[8], wf1[8], wf2[8];
        if (t < 500) {
            int wl = t / 25, wck = t % 25;
            const float* wp0 = (dir ? w2 : w1) + wl * HH + wck * 8;
            const float* wp1 = (dir ? w6 : w5) + wl * HH + wck * 8;
            const float* wp2 = (dir ? w8 : w7) + wl * HH + wck * 8;
            *(float4*)&wf0[0] = *(const float4*)wp0; *(float4*)&wf0[4] = *(const float4*)(wp0 + 4);
            *(float4*)&wf1[0] = *(const float4*)wp1; *(float4*)&wf1[4] = *(const float4*)(wp1 + 4);
            *(float4*)&wf2[0] = *(const float4*)wp2; *(float4*)&wf2[4] = *(const float4*)(wp2 + 4);
        }

        // ---- phase 2: attvec -> meanL / maxL; dsum folded; k unrolled x4, batched loads
        if (act) {
            int s = arow, h0 = ack * 8;
            float sm = 0.f;
            float ms[8], mx[8];
#pragma unroll
            for (int i = 0; i < 8; ++i) { ms[i] = 0.f; mx[i] = -INFINITY; }
            for (int kg = 0; kg < 16; ++kg) {
                int k0 = kg * 4;
                float4 av4 = *(const float4*)&S_L[s * SST + k0];
                bf16x8 o0 = *(const bf16x8*)&BT[(k0 + 0) * KST + h0];
                bf16x8 o1 = *(const bf16x8*)&BT[(k0 + 1) * KST + h0];
                bf16x8 o2 = *(const bf16x8*)&BT[(k0 + 2) * KST + h0];
                bf16x8 o3 = *(const bf16x8*)&BT[(k0 + 3) * KST + h0];
                sm += (av4.x + av4.y) + (av4.z + av4.w);
#pragma unroll
                for (int i = 0; i < 8; ++i) {
                    float t0 = av4.x * bf2f(o0[i]);
                    float t1 = av4.y * bf2f(o1[i]);
                    float t2 = av4.z * bf2f(o2[i]);
                    float t3 = av4.w * bf2f(o3[i]);
                    ms[i] += ((t0 + t1) + (t2 + t3));
                    mx[i] = fmaxf(mx[i], fmaxf(fmaxf(t0, t1), fmaxf(t2, t3)));
                }
            }
            float dsv = fmaxf(sm, EPS);
#pragma unroll
            for (int i = 0; i < 8; ++i) ms[i] /= dsv;
            *(float4*)&meanL[s * MHS + h0]     = *(float4*)&ms[0];
            *(float4*)&meanL[s * MHS + h0 + 4] = *(float4*)&ms[4];
            *(float4*)&maxL[s * MHS + h0]      = *(float4*)&mx[0];
            *(float4*)&maxL[s * MHS + h0 + 4]  = *(float4*)&mx[4];
        }
        __syncthreads();   // B4 — PB/WB overlays about to overwrite AT/BT/S_L

        // ---- phase 3: matches m=0 (full), m=1 (att_mean), m=2 (att_max)
#pragma unroll
        for (int m = 0; m < 3; ++m) {
            // stage products from registers/LDS (no global loads)
            if (act) {
                float yv[8];
                if (m == 0) {
#pragma unroll
                    for (int i = 0; i < 8; ++i) yv[i] = yv0[i];
                } else {
                    const float* yL = (m == 1 ? meanL : maxL) + arow * MHS + ack * 8;
                    *(float4*)&yv[0] = *(const float4*)yL;
                    *(float4*)&yv[4] = *(const float4*)(yL + 4);
                }
                __align__(16) __hip_bfloat16 r1[8], r2[8];
#pragma unroll
                for (int i = 0; i < 8; ++i) {
                    r1[i] = __float2bfloat16(xr[i] * yv[i]);
                    r2[i] = __float2bfloat16(yv[i] * yv[i]);
                }
                if (m == 0) {
                    __align__(16) __hip_bfloat16 r0[8];
#pragma unroll
                    for (int i = 0; i < 8; ++i) r0[i] = __float2bfloat16(xr[i] * xr[i]);
                    *(bf16x8*)&PB[(0 * 16 + arow) * KST + ack * 8] = *(bf16x8*)r0;
                }
                *(bf16x8*)&PB[(1 * 16 + arow) * KST + ack * 8] = *(bf16x8*)r1;
                *(bf16x8*)&PB[(2 * 16 + arow) * KST + ack * 8] = *(bf16x8*)r2;
            }
            // stage w^2 from registers
            if (t < 500) {
                int wl = t / 25, wck = t % 25;
                __align__(16) __hip_bfloat16 wr[8];
                if (m == 0) {
#pragma unroll
                    for (int i = 0; i < 8; ++i) wr[i] = __float2bfloat16(wf0[i] * wf0[i]);
                } else if (m == 1) {
#pragma unroll
                    for (int i = 0; i < 8; ++i) wr[i] = __float2bfloat16(wf1[i] * wf1[i]);
                } else {
#pragma unroll
                    for (int i = 0; i < 8; ++i) wr[i] = __float2bfloat16(wf2[i] * wf2[i]);
                }
                *(bf16x8*)&WB[wl * KST + wck * 8] = *(bf16x8*)wr;
            }
            if (m == 0) {
                // one-time zeros: PB pads (144), WB rows 20-31 (336), WB rows 0-19 pads (60)
                __align__(16) __hip_bfloat16 z8[8];
#pragma unroll
                for (int i = 0; i < 8; ++i) z8[i] = __float2bfloat16(0.f);
                for (int e = t; e < 540; e += 512) {
                    if (e < 144) { int row = e / 3, ckp = 25 + e % 3;
                        *(bf16x8*)&PB[row * KST + ckp * 8] = *(bf16x8*)z8;
                    } else if (e < 480) { int e2 = e - 144; int row = 20 + e2 / 28, ckp = e2 % 28;
                        *(bf16x8*)&WB[row * KST + ckp * 8] = *(bf16x8*)z8;
                    } else { int e2 = e - 480; int row = e2 / 3, ckp = 25 + e2 % 3;
                        *(bf16x8*)&WB[row * KST + ckp * 8] = *(bf16x8*)z8;
                    }
                }
            }
            __syncthreads();

            if (wv_ < 2) {
                int ntile = wv_;
                f32x4 accA = (f32x4){0.f, 0.f, 0.f, 0.f};
                f32x4 accD = (f32x4){0.f, 0.f, 0.f, 0.f};
                f32x4 accB = (f32x4){0.f, 0.f, 0.f, 0.f};
                for (int ks = 0; ks < 7; ++ks) {
                    int kb = ks * 32 + q * 8;
                    bf16x8 bfw = *(const bf16x8*)&WB[(ntile * 16 + c) * KST + kb];
                    bf16x8 a0 = *(const bf16x8*)&PB[(0 * 16 + c) * KST + kb];
                    bf16x8 a1 = *(const bf16x8*)&PB[(1 * 16 + c) * KST + kb];
                    bf16x8 a2 = *(const bf16x8*)&PB[(2 * 16 + c) * KST + kb];
                    accA = __builtin_amdgcn_mfma_f32_16x16x32_bf16(a0, bfw, accA, 0, 0, 0);
                    accD = __builtin_amdgcn_mfma_f32_16x16x32_bf16(a1, bfw, accD, 0, 0, 0);
                    accB = __builtin_amdgcn_mfma_f32_16x16x32_bf16(a2, bfw, accB, 0, 0, 0);
                }
                int l_ = ntile * 16 + c;
                if (l_ < LL) {
                    int chunk = (m == 0) ? 0 : (m == 1) ? 40 : 60;
#pragma unroll
                    for (int r = 0; r < 4; ++r) {
                        int s = qh * 16 + q * 4 + r;
                        float cosv = accD[r] / fmaxf(sqrtf(accA[r] * accB[r]), EPS);
                        out[side * (BB * SS * 160) + (b * SS + s) * 160 + dir * 80 + chunk + l_] = cosv;
                    }
                }
            }
            if (m < 2) __syncthreads();
        }
    } else {
        // ================================ type C: pairwise bf16 MFMA, diag norms
        __hip_bfloat16* AT = (__hip_bfloat16*)smem;            // 64*KST bf16
        __hip_bfloat16* BT = (__hip_bfloat16*)(smem + 7424);   // 64*KST bf16
        float* cmL = smem + 14848;                             // 256 fl
        float* nA  = smem + 15104;                             // 64
        float* nB  = smem + 15168;                             // 64
        int blk = grp * 5 + (rem - 2);   // 0..1279
        int l = blk % LL; int db = blk / LL; int b = db & 31; int dir = db >> 5;

        const float* wrow = (dir ? w4 : w3) + l * HH;
        const float* Ag = conp + dir * HH;
        const float* Bg = conh + dir * HH;

        // staging: 1792 items, 2x2 software pipeline (loads batched ahead of converts)
#pragma unroll
        for (int hf = 0; hf < 2; ++hf) {
            float qa[2][8], qb[2][8], qw[2][8];
#pragma unroll
            for (int r = 0; r < 2; ++r) {
                int e = t + (hf * 2 + r) * 512;
                int m = e / 28, ck = e - m * 28, k = ck * 8;
                if (e < 1792 && k < HH) {
                    const float* ap = Ag + (b * SS + m) * (2 * HH) + k;
                    const float* bp = Bg + (b * SS + m) * (2 * HH) + k;
                    const float* wp = wrow + k;
                    *(float4*)&qa[r][0] = *(const float4*)ap; *(float4*)&qa[r][4] = *(const float4*)(ap + 4);
                    *(float4*)&qb[r][0] = *(const float4*)bp; *(float4*)&qb[r][4] = *(const float4*)(bp + 4);
                    *(float4*)&qw[r][0] = *(const float4*)wp; *(float4*)&qw[r][4] = *(const float4*)(wp + 4);
                }
            }
#pragma unroll
            for (int r = 0; r < 2; ++r) {
                int e = t + (hf * 2 + r) * 512;
                if (e < 1792) {
                    int m = e / 28, ck = e - m * 28, k = ck * 8;
                    __align__(16) __hip_bfloat16 at8[8], bt8[8];
                    if (k < HH) {
#pragma unroll
                        for (int i = 0; i < 8; ++i) {
                            at8[i] = __float2bfloat16(qa[r][i] * qw[r][i]);
                            bt8[i] = __float2bfloat16(qb[r][i] * qw[r][i]);
                        }
                    } else {
#pragma unroll
                        for (int i = 0; i < 8; ++i) { at8[i] = __float2bfloat16(0.f); bt8[i] = __float2bfloat16(0.f); }
                    }
                    *(bf16x8*)&AT[m * KST + k] = *(bf16x8*)at8;
                    *(bf16x8*)&BT[m * KST + k] = *(bf16x8*)bt8;
                }
            }
        }
        __syncthreads();   // B1

        int wv_ = __builtin_amdgcn_readfirstlane(t >> 6);
        int lane = t & 63;
        int q = lane >> 4, c = lane & 15;
        int m0 = wv_ * 16;

        f32x4 acc[4];
#pragma unroll
        for (int ct = 0; ct < 4; ++ct) acc[ct] = (f32x4){0.f, 0.f, 0.f, 0.f};

        if (wv_ < 4) {
            for (int ks = 0; ks < 7; ++ks) {
                int kb = ks * 32 + q * 8;
                bf16x8 af = *(const bf16x8*)&AT[(m0 + c) * KST + kb];
#pragma unroll
                for (int ct = 0; ct < 4; ++ct) {
                    bf16x8 bf_ = *(const bf16x8*)&BT[(ct * 16 + c) * KST + kb];
                    acc[ct] = __builtin_amdgcn_mfma_f32_16x16x32_bf16(af, bf_, acc[ct], 0, 0, 0);
                }
            }
        } else {
            int d0 = (wv_ - 4) * 16;
            f32x4 accA = (f32x4){0.f, 0.f, 0.f, 0.f};
            f32x4 accB = (f32x4){0.f, 0.f, 0.f, 0.f};
            for (int ks = 0; ks < 7; ++ks) {
                int kb = ks * 32 + q * 8;
                bf16x8 af = *(const bf16x8*)&AT[(d0 + c) * KST + kb];
                bf16x8 bf_ = *(const bf16x8*)&BT[(d0 + c) * KST + kb];
                accA = __builtin_amdgcn_mfma_f32_16x16x32_bf16(af, af, accA, 0, 0, 0);
                accB = __builtin_amdgcn_mfma_f32_16x16x32_bf16(bf_, bf_, accB, 0, 0, 0);
            }
            if ((c >> 2) == q) { nA[d0 + c] = accA[c & 3]; nB[d0 + c] = accB[c & 3]; }
        }
        __syncthreads();   // B2 — diag norms visible

        if (wv_ < 4) {
            float na[4], nb[4];
#pragma unroll
            for (int r = 0; r < 4; ++r) na[r] = sqrtf(nA[m0 + q * 4 + r]);
#pragma unroll
            for (int ct = 0; ct < 4; ++ct) nb[ct] = sqrtf(nB[ct * 16 + c]);

            float rowm[4] = {-INFINITY, -INFINITY, -INFINITY, -INFINITY};
            float colm[4] = {-INFINITY, -INFINITY, -INFINITY, -INFINITY};
#pragma unroll
            for (int ct = 0; ct < 4; ++ct) {
#pragma unroll
                for (int r = 0; r < 4; ++r) {
                    float cv = acc[ct][r] / fmaxf(na[r] * nb[ct], EPS);
                    rowm[r] = fmaxf(rowm[r], cv);
                    colm[ct] = fmaxf(colm[ct], cv);
                }
            }

#pragma unroll
            for (int r = 0; r < 4; ++r) {
                float v = rowm[r];
                v = fmaxf(v, __shfl_xor(v, 1, 64));
                v = fmaxf(v, __shfl_xor(v, 2, 64));
                v = fmaxf(v, __shfl_xor(v, 4, 64));
                v = fmaxf(v, __shfl_xor(v, 8, 64));
                rowm[r] = v;
            }
            if (c == 0) {
#pragma unroll
                for (int r = 0; r < 4; ++r) {
                    int i = m0 + q * 4 + r;
                    out[(b * SS + i) * 160 + dir * 80 + 20 + l] = rowm[r];
                }
            }

#pragma unroll
            for (int ct = 0; ct < 4; ++ct) {
                float v = colm[ct];
                v = fmaxf(v, __shfl_xor(v, 16, 64));
                v = fmaxf(v, __shfl_xor(v, 32, 64));
                colm[ct] = v;
            }
            if (q == 0) {
#pragma unroll
                for (int ct = 0; ct < 4; ++ct) cmL[wv_ * 64 + ct * 16 + c] = colm[ct];
            }
        }
        __syncthreads();   // B3
        if (t < 64) {
            float m = fmaxf(fmaxf(cmL[t], cmL[64 + t]), fmaxf(cmL[128 + t], cmL[192 + t]));
            out[BB * SS * 160 + (b * SS + t) * 160 + dir * 80 + 20 + l] = m;
        }
    }
}

extern "C" void kernel_launch(void* const* d_in, const int* in_sizes, int n_in,
                              void* d_out, int out_size, void* d_ws, size_t ws_size,
                              hipStream_t stream) {
    const float* conp = (const float*)d_in[0];
    const float* conh = (const float*)d_in[1];
    const float* w1 = (const float*)d_in[2];
    const float* w2 = (const float*)d_in[3];
    const float* w3 = (const float*)d_in[4];
    const float* w4 = (const float*)d_in[5];
    const float* w5 = (const float*)d_in[6];
    const float* w6 = (const float*)d_in[7];
    const float* w7 = (const float*)d_in[8];
    const float* w8 = (const float*)d_in[9];
    float* out = (float*)d_out;
    (void)d_ws; (void)ws_size;

    fused_all_kernel<<<1792, 512, 0, stream>>>(conp, conh,
                                               w1, w2, w3, w4, w5, w6, w7, w8, out);
}

// Round 7
// 116.443 us; speedup vs baseline: 1.0201x; 1.0201x over previous
//
#include <hip/hip_runtime.h>
#include <hip/hip_bf16.h>
#include <math.h>

#define EPS 1e-8f
#define BB 32
#define SS 64
#define HH 200
#define LL 20
#define KST 232   // bf16 LDS row stride
#define SST 68    // S-tile LDS row stride (floats)
#define MHS 200   // mean/max LDS row stride (floats)

typedef short bf16x8 __attribute__((ext_vector_type(8)));
typedef float f32x4 __attribute__((ext_vector_type(4)));

__device__ inline float bf2f(short u) {
    union { unsigned int i; float f; } v;
    v.i = ((unsigned int)(unsigned short)u) << 16;
    return v.f;
}

// ONE kernel, grid 1792 x 512 (256 groups of 7: 2 type-A + 5 type-C). No workspace.
// r7 = r5 verbatim + XCD-aware block swizzle: wg = (bid&7)*224 + (bid>>3).
// Consecutive blockIdx round-robin across XCDs; the swizzle gives each XCD a
// contiguous 224-wg chunk, so the 20 l-blocks sharing one (dir,b)'s rows hit
// the same per-XCD L2 (staging becomes L2-hit instead of 5x HBM re-fetch).
//
// Type A LDS (floats, 19392 = 77.6 KB -> 2 blocks/CU):
//   [0,1856)       AT 16xKST bf16      \ overlay PB 48xKST bf16 [0,5568)
//   [1856,9280)    BT 64xKST bf16      /
//   [9280,10368)   S_L 16xSST f32      \ overlay WB 32xKST bf16 [9280,12992)
//   [10368,10448)  nrmA(16) nrmB(64)   /
//   [12992,16192)  meanL 16x200 f32
//   [16192,19392)  maxL  16x200 f32
// Type C LDS: AT 64xKST [0,7424) | BT [7424,14848) | cmL [14848,15104)
//             nA [15104,15168) | nB [15168,15232)
__global__ __launch_bounds__(512) void fused_all_kernel(
        const float* __restrict__ conp, const float* __restrict__ conh,
        const float* __restrict__ w1, const float* __restrict__ w2,
        const float* __restrict__ w3, const float* __restrict__ w4,
        const float* __restrict__ w5, const float* __restrict__ w6,
        const float* __restrict__ w7, const float* __restrict__ w8,
        float* __restrict__ out) {
    __shared__ __align__(16) float smem[19392];
    int t = threadIdx.x;

    // XCD-aware swizzle (bijective on [0,1792)): XCD x serves wg in [224x, 224x+224)
    int wg = ((blockIdx.x & 7) * 224) + (blockIdx.x >> 3);
    int grp = wg / 7;
    int rem = wg % 7;

    if (rem < 2) {
        // ================================ type A (16 self-rows)
        __hip_bfloat16* AT = (__hip_bfloat16*)smem;
        __hip_bfloat16* BT = (__hip_bfloat16*)(smem + 1856);
        float* S_L  = smem + 9280;
        float* nrmA = smem + 10368;
        float* nrmB = smem + 10384;
        __hip_bfloat16* PB = (__hip_bfloat16*)smem;            // phase 3: 48xKST
        __hip_bfloat16* WB = (__hip_bfloat16*)(smem + 9280);   // phase 3: 32xKST
        float* meanL = smem + 12992;
        float* maxL  = smem + 16192;

        int blk = grp * 2 + rem;       // 0..511
        int qh = blk & 3;              // 16-row quarter of self side
        int sdb = blk >> 2;
        int b = sdb & 31, sd = sdb >> 5;
        int dir = sd & 1, side = sd >> 1;
        const float* selfb = side ? conh : conp;
        const float* oppb  = side ? conp : conh;
        int fidx = dir ? 0 : (SS - 1);
        const float* fvr = oppb + (b * SS + fidx) * (2 * HH) + dir * HH;

        int arow = t / 25, ack = t % 25;   // phase-1/2/3 mapping for t<400 / t<500

        // ---- phase 1: stage 16 self rows (regs kept) + fvr prefetch + 64 opp rows + pads
        float xr[8], yv0[8];
        if (t < 400) {
            const float* xp = selfb + (b * SS + qh * 16 + arow) * (2 * HH) + dir * HH + ack * 8;
            *(float4*)&xr[0] = *(const float4*)xp; *(float4*)&xr[4] = *(const float4*)(xp + 4);
            *(float4*)&yv0[0] = *(const float4*)(fvr + ack * 8);
            *(float4*)&yv0[4] = *(const float4*)(fvr + ack * 8 + 4);
            __align__(16) __hip_bfloat16 r8[8];
#pragma unroll
            for (int i = 0; i < 8; ++i) r8[i] = __float2bfloat16(xr[i]);
            *(bf16x8*)&AT[arow * KST + ack * 8] = *(bf16x8*)r8;
        }
        {
            __align__(16) __hip_bfloat16 z8[8];
#pragma unroll
            for (int i = 0; i < 8; ++i) z8[i] = __float2bfloat16(0.f);
            // pads: AT rows 0-15 ck 25-27 (48) + BT rows 0-63 ck 25-27 (192)
            if (t < 240) {
                if (t < 48) { int row = t / 3, ckp = 25 + t % 3;
                    *(bf16x8*)&AT[row * KST + ckp * 8] = *(bf16x8*)z8;
                } else { int e2 = t - 48; int row = e2 / 3, ckp = 25 + e2 % 3;
                    *(bf16x8*)&BT[row * KST + ckp * 8] = *(bf16x8*)z8;
                }
            }
        }
        for (int e = t; e < 1600; e += 512) {
            int rw = e / 25, ck = e % 25, k = ck * 8;
            const float* xp = oppb + (b * SS + rw) * (2 * HH) + dir * HH + k;
            float xv[8];
            *(float4*)&xv[0] = *(const float4*)xp; *(float4*)&xv[4] = *(const float4*)(xp + 4);
            __align__(16) __hip_bfloat16 r8[8];
#pragma unroll
            for (int i = 0; i < 8; ++i) r8[i] = __float2bfloat16(xv[i]);
            *(bf16x8*)&BT[rw * KST + k] = *(bf16x8*)r8;
        }
        __syncthreads();   // B1

        int wv_ = __builtin_amdgcn_readfirstlane(t >> 6);
        int lane = t & 63;
        int q = lane >> 4, c = lane & 15;

        // ---- MFMA: waves 0-3 raw S-tiles; waves 4-7 norm diagonals
        if (wv_ < 4) {
            int ct = wv_;
            f32x4 acc = (f32x4){0.f, 0.f, 0.f, 0.f};
            for (int ks = 0; ks < 7; ++ks) {
                int kb = ks * 32 + q * 8;
                bf16x8 af  = *(const bf16x8*)&AT[c * KST + kb];
                bf16x8 bf_ = *(const bf16x8*)&BT[(ct * 16 + c) * KST + kb];
                acc = __builtin_amdgcn_mfma_f32_16x16x32_bf16(af, bf_, acc, 0, 0, 0);
            }
            int col = ct * 16 + c;
#pragma unroll
            for (int r = 0; r < 4; ++r) S_L[(q * 4 + r) * SST + col] = acc[r];   // raw dot
        } else {
            int dt = wv_ - 4;
            f32x4 accB = (f32x4){0.f, 0.f, 0.f, 0.f};
            for (int ks = 0; ks < 7; ++ks) {
                int kb = ks * 32 + q * 8;
                bf16x8 bf_ = *(const bf16x8*)&BT[(dt * 16 + c) * KST + kb];
                accB = __builtin_amdgcn_mfma_f32_16x16x32_bf16(bf_, bf_, accB, 0, 0, 0);
            }
            if ((c >> 2) == q) nrmB[dt * 16 + c] = accB[c & 3];
            if (dt == 0) {   // wave 4 also does the 16-row A diagonal
                f32x4 accA = (f32x4){0.f, 0.f, 0.f, 0.f};
                for (int ks = 0; ks < 7; ++ks) {
                    int kb = ks * 32 + q * 8;
                    bf16x8 af = *(const bf16x8*)&AT[c * KST + kb];
                    accA = __builtin_amdgcn_mfma_f32_16x16x32_bf16(af, af, accA, 0, 0, 0);
                }
                if ((c >> 2) == q) nrmA[c] = accA[c & 3];
            }
        }
        __syncthreads();   // B2

        // ---- normalize S in place (1024 elems, 2/thread)
        for (int e = t; e < 1024; e += 512) {
            int r_ = e >> 6, cc = e & 63;
            float ns = sqrtf(nrmA[r_]), no = sqrtf(nrmB[cc]);
            S_L[r_ * SST + cc] = S_L[r_ * SST + cc] / fmaxf(ns * no, EPS);
        }
        __syncthreads();   // B3

        // ---- prefetch all three w rows for phase 3 (latency hides under phase 2)
        float wf0[8], wf1[8], wf2[8];
        if (t < 500) {
            int wl = t / 25, wck = t % 25;
            const float* wp0 = (dir ? w2 : w1) + wl * HH + wck * 8;
            const float* wp1 = (dir ? w6 : w5) + wl * HH + wck * 8;
            const float* wp2 = (dir ? w8 : w7) + wl * HH + wck * 8;
            *(float4*)&wf0[0] = *(const float4*)wp0; *(float4*)&wf0[4] = *(const float4*)(wp0 + 4);
            *(float4*)&wf1[0] = *(const float4*)wp1; *(float4*)&wf1[4] = *(const float4*)(wp1 + 4);
            *(float4*)&wf2[0] = *(const float4*)wp2; *(float4*)&wf2[4] = *(const float4*)(wp2 + 4);
        }

        // ---- phase 2: attvec -> meanL / maxL; dsum folded per-thread
        if (t < 400) {
            int s = arow, h0 = ack * 8;
            float sm = 0.f;
            float ms[8], mx[8];
#pragma unroll
            for (int i = 0; i < 8; ++i) { ms[i] = 0.f; mx[i] = -INFINITY; }
            for (int k = 0; k < 64; ++k) {
                float a = S_L[s * SST + k];
                sm += a;
                bf16x8 ov = *(const bf16x8*)&BT[k * KST + h0];
#pragma unroll
                for (int i = 0; i < 8; ++i) {
                    float tt = a * bf2f(ov[i]);
                    ms[i] += tt;
                    mx[i] = fmaxf(mx[i], tt);
                }
            }
            float dsv = fmaxf(sm, EPS);
#pragma unroll
            for (int i = 0; i < 8; ++i) ms[i] /= dsv;
            *(float4*)&meanL[s * MHS + h0]     = *(float4*)&ms[0];
            *(float4*)&meanL[s * MHS + h0 + 4] = *(float4*)&ms[4];
            *(float4*)&maxL[s * MHS + h0]      = *(float4*)&mx[0];
            *(float4*)&maxL[s * MHS + h0 + 4]  = *(float4*)&mx[4];
        }
        __syncthreads();   // B4 — PB/WB overlays about to overwrite AT/BT/S_L

        // ---- phase 3: matches m=0 (full), m=1 (att_mean), m=2 (att_max)
#pragma unroll
        for (int m = 0; m < 3; ++m) {
            // stage products from registers/LDS (no global loads)
            if (t < 400) {
                float yv[8];
                if (m == 0) {
#pragma unroll
                    for (int i = 0; i < 8; ++i) yv[i] = yv0[i];
                } else {
                    const float* yL = (m == 1 ? meanL : maxL) + arow * MHS + ack * 8;
                    *(float4*)&yv[0] = *(const float4*)yL;
                    *(float4*)&yv[4] = *(const float4*)(yL + 4);
                }
                __align__(16) __hip_bfloat16 r1[8], r2[8];
#pragma unroll
                for (int i = 0; i < 8; ++i) {
                    r1[i] = __float2bfloat16(xr[i] * yv[i]);
                    r2[i] = __float2bfloat16(yv[i] * yv[i]);
                }
                if (m == 0) {
                    __align__(16) __hip_bfloat16 r0[8];
#pragma unroll
                    for (int i = 0; i < 8; ++i) r0[i] = __float2bfloat16(xr[i] * xr[i]);
                    *(bf16x8*)&PB[(0 * 16 + arow) * KST + ack * 8] = *(bf16x8*)r0;
                }
                *(bf16x8*)&PB[(1 * 16 + arow) * KST + ack * 8] = *(bf16x8*)r1;
                *(bf16x8*)&PB[(2 * 16 + arow) * KST + ack * 8] = *(bf16x8*)r2;
            }
            // stage w^2 from registers
            if (t < 500) {
                int wl = t / 25, wck = t % 25;
                __align__(16) __hip_bfloat16 wr[8];
                if (m == 0) {
#pragma unroll
                    for (int i = 0; i < 8; ++i) wr[i] = __float2bfloat16(wf0[i] * wf0[i]);
                } else if (m == 1) {
#pragma unroll
                    for (int i = 0; i < 8; ++i) wr[i] = __float2bfloat16(wf1[i] * wf1[i]);
                } else {
#pragma unroll
                    for (int i = 0; i < 8; ++i) wr[i] = __float2bfloat16(wf2[i] * wf2[i]);
                }
                *(bf16x8*)&WB[wl * KST + wck * 8] = *(bf16x8*)wr;
            }
            if (m == 0) {
                // one-time zeros: PB pads (144), WB rows 20-31 (336), WB rows 0-19 pads (60)
                __align__(16) __hip_bfloat16 z8[8];
#pragma unroll
                for (int i = 0; i < 8; ++i) z8[i] = __float2bfloat16(0.f);
                for (int e = t; e < 540; e += 512) {
                    if (e < 144) { int row = e / 3, ckp = 25 + e % 3;
                        *(bf16x8*)&PB[row * KST + ckp * 8] = *(bf16x8*)z8;
                    } else if (e < 480) { int e2 = e - 144; int row = 20 + e2 / 28, ckp = e2 % 28;
                        *(bf16x8*)&WB[row * KST + ckp * 8] = *(bf16x8*)z8;
                    } else { int e2 = e - 480; int row = e2 / 3, ckp = 25 + e2 % 3;
                        *(bf16x8*)&WB[row * KST + ckp * 8] = *(bf16x8*)z8;
                    }
                }
            }
            __syncthreads();

            if (wv_ < 2) {
                int ntile = wv_;
                f32x4 accA = (f32x4){0.f, 0.f, 0.f, 0.f};
                f32x4 accD = (f32x4){0.f, 0.f, 0.f, 0.f};
                f32x4 accB = (f32x4){0.f, 0.f, 0.f, 0.f};
                for (int ks = 0; ks < 7; ++ks) {
                    int kb = ks * 32 + q * 8;
                    bf16x8 bfw = *(const bf16x8*)&WB[(ntile * 16 + c) * KST + kb];
                    bf16x8 a0 = *(const bf16x8*)&PB[(0 * 16 + c) * KST + kb];
                    bf16x8 a1 = *(const bf16x8*)&PB[(1 * 16 + c) * KST + kb];
                    bf16x8 a2 = *(const bf16x8*)&PB[(2 * 16 + c) * KST + kb];
                    accA = __builtin_amdgcn_mfma_f32_16x16x32_bf16(a0, bfw, accA, 0, 0, 0);
                    accD = __builtin_amdgcn_mfma_f32_16x16x32_bf16(a1, bfw, accD, 0, 0, 0);
                    accB = __builtin_amdgcn_mfma_f32_16x16x32_bf16(a2, bfw, accB, 0, 0, 0);
                }
                int l_ = ntile * 16 + c;
                if (l_ < LL) {
                    int chunk = (m == 0) ? 0 : (m == 1) ? 40 : 60;
#pragma unroll
                    for (int r = 0; r < 4; ++r) {
                        int s = qh * 16 + q * 4 + r;
                        float cosv = accD[r] / fmaxf(sqrtf(accA[r] * accB[r]), EPS);
                        out[side * (BB * SS * 160) + (b * SS + s) * 160 + dir * 80 + chunk + l_] = cosv;
                    }
                }
            }
            if (m < 2) __syncthreads();
        }
    } else {
        // ================================ type C: pairwise bf16 MFMA, diag norms
        __hip_bfloat16* AT = (__hip_bfloat16*)smem;            // 64*KST bf16
        __hip_bfloat16* BT = (__hip_bfloat16*)(smem + 7424);   // 64*KST bf16
        float* cmL = smem + 14848;                             // 256 fl
        float* nA  = smem + 15104;                             // 64
        float* nB  = smem + 15168;                             // 64
        int blk = grp * 5 + (rem - 2);   // 0..1279
        int l = blk % LL; int db = blk / LL; int b = db & 31; int dir = db >> 5;

        const float* wrow = (dir ? w4 : w3) + l * HH;
        const float* Ag = conp + dir * HH;
        const float* Bg = conh + dir * HH;

        for (int e = t; e < 64 * 28; e += 512) {
            int m = e / 28, ck = e - m * 28;
            int k = ck * 8;
            __align__(16) __hip_bfloat16 at8[8];
            __align__(16) __hip_bfloat16 bt8[8];
            if (k < HH) {
                const float* ap = Ag + (b * SS + m) * (2 * HH) + k;
                const float* bp = Bg + (b * SS + m) * (2 * HH) + k;
                const float* wp = wrow + k;
                float av[8], bv[8], wvv[8];
                *(float4*)&av[0]  = *(const float4*)ap; *(float4*)&av[4]  = *(const float4*)(ap + 4);
                *(float4*)&bv[0]  = *(const float4*)bp; *(float4*)&bv[4]  = *(const float4*)(bp + 4);
                *(float4*)&wvv[0] = *(const float4*)wp; *(float4*)&wvv[4] = *(const float4*)(wp + 4);
#pragma unroll
                for (int i = 0; i < 8; ++i) {
                    at8[i] = __float2bfloat16(av[i] * wvv[i]);
                    bt8[i] = __float2bfloat16(bv[i] * wvv[i]);
                }
            } else {
#pragma unroll
                for (int ii = 0; ii < 8; ++ii) { at8[ii] = __float2bfloat16(0.f); bt8[ii] = __float2bfloat16(0.f); }
            }
            *(bf16x8*)&AT[m * KST + k] = *(bf16x8*)at8;
            *(bf16x8*)&BT[m * KST + k] = *(bf16x8*)bt8;
        }
        __syncthreads();   // B1

        int wv_ = __builtin_amdgcn_readfirstlane(t >> 6);
        int lane = t & 63;
        int q = lane >> 4, c = lane & 15;
        int m0 = wv_ * 16;

        f32x4 acc[4];
#pragma unroll
        for (int ct = 0; ct < 4; ++ct) acc[ct] = (f32x4){0.f, 0.f, 0.f, 0.f};

        if (wv_ < 4) {
            for (int ks = 0; ks < 7; ++ks) {
                int kb = ks * 32 + q * 8;
                bf16x8 af = *(const bf16x8*)&AT[(m0 + c) * KST + kb];
#pragma unroll
                for (int ct = 0; ct < 4; ++ct) {
                    bf16x8 bf_ = *(const bf16x8*)&BT[(ct * 16 + c) * KST + kb];
                    acc[ct] = __builtin_amdgcn_mfma_f32_16x16x32_bf16(af, bf_, acc[ct], 0, 0, 0);
                }
            }
        } else {
            int d0 = (wv_ - 4) * 16;
            f32x4 accA = (f32x4){0.f, 0.f, 0.f, 0.f};
            f32x4 accB = (f32x4){0.f, 0.f, 0.f, 0.f};
            for (int ks = 0; ks < 7; ++ks) {
                int kb = ks * 32 + q * 8;
                bf16x8 af = *(const bf16x8*)&AT[(d0 + c) * KST + kb];
                bf16x8 bf_ = *(const bf16x8*)&BT[(d0 + c) * KST + kb];
                accA = __builtin_amdgcn_mfma_f32_16x16x32_bf16(af, af, accA, 0, 0, 0);
                accB = __builtin_amdgcn_mfma_f32_16x16x32_bf16(bf_, bf_, accB, 0, 0, 0);
            }
            if ((c >> 2) == q) { nA[d0 + c] = accA[c & 3]; nB[d0 + c] = accB[c & 3]; }
        }
        __syncthreads();   // B2 — diag norms visible

        if (wv_ < 4) {
            float na[4], nb[4];
#pragma unroll
            for (int r = 0; r < 4; ++r) na[r] = sqrtf(nA[m0 + q * 4 + r]);
#pragma unroll
            for (int ct = 0; ct < 4; ++ct) nb[ct] = sqrtf(nB[ct * 16 + c]);

            float rowm[4] = {-INFINITY, -INFINITY, -INFINITY, -INFINITY};
            float colm[4] = {-INFINITY, -INFINITY, -INFINITY, -INFINITY};
#pragma unroll
            for (int ct = 0; ct < 4; ++ct) {
#pragma unroll
                for (int r = 0; r < 4; ++r) {
                    float cv = acc[ct][r] / fmaxf(na[r] * nb[ct], EPS);
                    rowm[r] = fmaxf(rowm[r], cv);
                    colm[ct] = fmaxf(colm[ct], cv);
                }
            }

#pragma unroll
            for (int r = 0; r < 4; ++r) {
                float v = rowm[r];
                v = fmaxf(v, __shfl_xor(v, 1, 64));
                v = fmaxf(v, __shfl_xor(v, 2, 64));
                v = fmaxf(v, __shfl_xor(v, 4, 64));
                v = fmaxf(v, __shfl_xor(v, 8, 64));
                rowm[r] = v;
            }
            if (c == 0) {
#pragma unroll
                for (int r = 0; r < 4; ++r) {
                    int i = m0 + q * 4 + r;
                    out[(b * SS + i) * 160 + dir * 80 + 20 + l] = rowm[r];
                }
            }

#pragma unroll
            for (int ct = 0; ct < 4; ++ct) {
                float v = colm[ct];
                v = fmaxf(v, __shfl_xor(v, 16, 64));
                v = fmaxf(v, __shfl_xor(v, 32, 64));
                colm[ct] = v;
            }
            if (q == 0) {
#pragma unroll
                for (int ct = 0; ct < 4; ++ct) cmL[wv_ * 64 + ct * 16 + c] = colm[ct];
            }
        }
        __syncthreads();   // B3
        if (t < 64) {
            float m = fmaxf(fmaxf(cmL[t], cmL[64 + t]), fmaxf(cmL[128 + t], cmL[192 + t]));
            out[BB * SS * 160 + (b * SS + t) * 160 + dir * 80 + 20 + l] = m;
        }
    }
}

extern "C" void kernel_launch(void* const* d_in, const int* in_sizes, int n_in,
                              void* d_out, int out_size, void* d_ws, size_t ws_size,
                              hipStream_t stream) {
    const float* conp = (const float*)d_in[0];
    const float* conh = (const float*)d_in[1];
    const float* w1 = (const float*)d_in[2];
    const float* w2 = (const float*)d_in[3];
    const float* w3 = (const float*)d_in[4];
    const float* w4 = (const float*)d_in[5];
    const float* w5 = (const float*)d_in[6];
    const float* w6 = (const float*)d_in[7];
    const float* w7 = (const float*)d_in[8];
    const float* w8 = (const float*)d_in[9];
    float* out = (float*)d_out;
    (void)d_ws; (void)ws_size;

    fused_all_kernel<<<1792, 512, 0, stream>>>(conp, conh,
                                               w1, w2, w3, w4, w5, w6, w7, w8, out);
}

// Round 9
// 107.413 us; speedup vs baseline: 1.1059x; 1.0841x over previous
//
#include <hip/hip_runtime.h>
#include <hip/hip_bf16.h>
#include <math.h>

#define EPS 1e-8f
#define BB 32
#define SS 64
#define HH 200
#define LL 20
#define KST 232   // f16/bf16 LDS row stride (464B -> 2-way bank walk)
#define S16ST 72  // S16 row stride (f16)
#define BHST 72   // BH row stride (f16)
#define MLST 208  // meanL row stride (f16)

typedef short bf16x8 __attribute__((ext_vector_type(8)));
typedef float f32x4 __attribute__((ext_vector_type(4)));
typedef _Float16 f16x8v __attribute__((ext_vector_type(8)));
typedef _Float16 f16x2 __attribute__((ext_vector_type(2)));

// ONE kernel, grid 1792 x 512 (256 groups of 7: 2 type-A + 5 type-C). No workspace.
// r9 = r8 with the f16-overflow fix: m=1 matches against the RAW mean numerator
// (cosine is invariant to the reference's always-positive per-row divisor), scaled
// x0.125 so y^2 stays far below f16 max. dsum deleted. Max-loop S reads vectorized.
// Type C is r7-VERBATIM (bf16). XCD swizzle kept.
//
// Type A LDS (floats, 19104 = 76.4 KB -> 2 blocks/CU):
//   [0,1856)       AT16 16xKST f16     \ overlay PB 48xKST f16 [0,5568)
//   [1856,9280)    BT16 64xKST f16     /         WB 32xKST f16 [5568,9280)
//   [9280,16768)   BH 208xBHST f16 (B transposed, rows 200-207 zeroed)
//   [16768,17344)  S16 16xS16ST f16 (normalized cos)
//   [17344,17360)  nrmA(16)  [17360,17424) nrmB(64)
//   [17440,19104)  meanL 16xMLST f16 (0.125 * raw numerator)
// Type C LDS: AT 64xKST [0,7424) | BT [7424,14848) | cmL [14848,15104)
//             nA [15104,15168) | nB [15168,15232)
__global__ __launch_bounds__(512) void fused_all_kernel(
        const float* __restrict__ conp, const float* __restrict__ conh,
        const float* __restrict__ w1, const float* __restrict__ w2,
        const float* __restrict__ w3, const float* __restrict__ w4,
        const float* __restrict__ w5, const float* __restrict__ w6,
        const float* __restrict__ w7, const float* __restrict__ w8,
        float* __restrict__ out) {
    __shared__ __align__(16) float smem[19104];
    int t = threadIdx.x;

    // XCD-aware swizzle (bijective on [0,1792))
    int wg = ((blockIdx.x & 7) * 224) + (blockIdx.x >> 3);
    int grp = wg / 7;
    int rem = wg % 7;

    if (rem < 2) {
        // ================================ type A (16 self-rows, f16)
        _Float16* AT16 = (_Float16*)smem;
        _Float16* BT16 = (_Float16*)(smem + 1856);
        _Float16* BHh  = (_Float16*)(smem + 9280);
        _Float16* S16h = (_Float16*)(smem + 16768);
        float* nrmA  = smem + 17344;
        float* nrmB  = smem + 17360;
        _Float16* meanLh = (_Float16*)(smem + 17440);
        _Float16* PB = (_Float16*)smem;            // phase 3: 48xKST
        _Float16* WB = (_Float16*)(smem + 5568);   // phase 3: 32xKST

        int blk = grp * 2 + rem;       // 0..511
        int qh = blk & 3;              // 16-row quarter of self side
        int sdb = blk >> 2;
        int b = sdb & 31, sd = sdb >> 5;
        int dir = sd & 1, side = sd >> 1;
        const float* selfb = side ? conh : conp;
        const float* oppb  = side ? conp : conh;
        int fidx = dir ? 0 : (SS - 1);
        const float* fvr = oppb + (b * SS + fidx) * (2 * HH) + dir * HH;

        int arow = t / 25, ack = t % 25;   // mapping for t<400 / t<500

        // ---- phase 1: stage 16 self rows (regs kept) + fvr prefetch + 64 opp rows + pads
        float xr[8], yv0[8];
        if (t < 400) {
            const float* xp = selfb + (b * SS + qh * 16 + arow) * (2 * HH) + dir * HH + ack * 8;
            *(float4*)&xr[0] = *(const float4*)xp; *(float4*)&xr[4] = *(const float4*)(xp + 4);
            *(float4*)&yv0[0] = *(const float4*)(fvr + ack * 8);
            *(float4*)&yv0[4] = *(const float4*)(fvr + ack * 8 + 4);
            f16x8v r8;
#pragma unroll
            for (int i = 0; i < 8; ++i) r8[i] = (_Float16)xr[i];
            *(f16x8v*)&AT16[arow * KST + ack * 8] = r8;
        }
        {
            f16x8v z8 = (f16x8v)(_Float16)0.f;
            if (t < 312) {
                if (t < 48) { int row = t / 3, ckp = 25 + t % 3;
                    *(f16x8v*)&AT16[row * KST + ckp * 8] = z8;
                } else if (t < 240) { int e2 = t - 48; int row = e2 / 3, ckp = 25 + e2 % 3;
                    *(f16x8v*)&BT16[row * KST + ckp * 8] = z8;
                } else { int e2 = t - 240; int row = 200 + e2 / 9, c8 = (e2 % 9) * 8;
                    *(f16x8v*)&BHh[row * BHST + c8] = z8;
                }
            }
        }
        for (int e = t; e < 1600; e += 512) {
            int rw = e / 25, ck = e % 25, k = ck * 8;
            const float* xp = oppb + (b * SS + rw) * (2 * HH) + dir * HH + k;
            float xv[8];
            *(float4*)&xv[0] = *(const float4*)xp; *(float4*)&xv[4] = *(const float4*)(xp + 4);
            f16x8v r8;
#pragma unroll
            for (int i = 0; i < 8; ++i) r8[i] = (_Float16)xv[i];
            *(f16x8v*)&BT16[rw * KST + k] = r8;
        }
        __syncthreads();   // B1

        int wv_ = __builtin_amdgcn_readfirstlane(t >> 6);
        int lane = t & 63;
        int q = lane >> 4, c = lane & 15;

        // ---- MFMA phase: waves 0-3 S-tiles (acc held in regs); waves 4-7 diag norms;
        //      waves 5-7 also build BH = B^T (for the mean GEMM)
        f32x4 accS = (f32x4){0.f, 0.f, 0.f, 0.f};
        if (wv_ < 4) {
            int ct = wv_;
            for (int ks = 0; ks < 7; ++ks) {
                int kb = ks * 32 + q * 8;
                f16x8v af  = *(const f16x8v*)&AT16[c * KST + kb];
                f16x8v bf_ = *(const f16x8v*)&BT16[(ct * 16 + c) * KST + kb];
                accS = __builtin_amdgcn_mfma_f32_16x16x32_f16(af, bf_, accS, 0, 0, 0);
            }
        } else {
            int dt = wv_ - 4;
            f32x4 accB = (f32x4){0.f, 0.f, 0.f, 0.f};
            for (int ks = 0; ks < 7; ++ks) {
                int kb = ks * 32 + q * 8;
                f16x8v bf_ = *(const f16x8v*)&BT16[(dt * 16 + c) * KST + kb];
                accB = __builtin_amdgcn_mfma_f32_16x16x32_f16(bf_, bf_, accB, 0, 0, 0);
            }
            if ((c >> 2) == q) nrmB[dt * 16 + c] = accB[c & 3];
            if (dt == 0) {   // wave 4: A diagonal
                f32x4 accA = (f32x4){0.f, 0.f, 0.f, 0.f};
                for (int ks = 0; ks < 7; ++ks) {
                    int kb = ks * 32 + q * 8;
                    f16x8v af = *(const f16x8v*)&AT16[c * KST + kb];
                    accA = __builtin_amdgcn_mfma_f32_16x16x32_f16(af, af, accA, 0, 0, 0);
                }
                if ((c >> 2) == q) nrmA[c] = accA[c & 3];
            } else {         // waves 5-7: transpose BT -> BH (lane = opp row j)
                for (int ch = dt - 1; ch < 25; ch += 3) {
                    f16x8v v = *(const f16x8v*)&BT16[lane * KST + ch * 8];
#pragma unroll
                    for (int i = 0; i < 8; ++i) BHh[(ch * 8 + i) * BHST + lane] = v[i];
                }
            }
        }
        __syncthreads();   // B2 — norms + BH visible

        // ---- S-waves write normalized cos directly to S16 (f16)
        if (wv_ < 4) {
            int col = wv_ * 16 + c;
            float no = sqrtf(nrmB[col]);
#pragma unroll
            for (int r = 0; r < 4; ++r) {
                int row = q * 4 + r;
                float ns = sqrtf(nrmA[row]);
                S16h[row * S16ST + col] = (_Float16)(accS[r] / fmaxf(ns * no, EPS));
            }
        }
        __syncthreads();   // B3 — S16 complete

        // ---- prefetch all three w rows for phase 3
        float wf0[8], wf1[8], wf2[8];
        if (t < 500) {
            int wl = t / 25, wck = t % 25;
            const float* wp0 = (dir ? w2 : w1) + wl * HH + wck * 8;
            const float* wp1 = (dir ? w6 : w5) + wl * HH + wck * 8;
            const float* wp2 = (dir ? w8 : w7) + wl * HH + wck * 8;
            *(float4*)&wf0[0] = *(const float4*)wp0; *(float4*)&wf0[4] = *(const float4*)(wp0 + 4);
            *(float4*)&wf1[0] = *(const float4*)wp1; *(float4*)&wf1[4] = *(const float4*)(wp1 + 4);
            *(float4*)&wf2[0] = *(const float4*)wp2; *(float4*)&wf2[4] = *(const float4*)(wp2 + 4);
        }

        // ---- phase 2: wave 7 = mean GEMM (S16 @ BH, f32 acc, x0.125); waves 0-6 = f16 max
        f16x2 mx0, mx1, mx2, mx3;
        {
            f16x2 ninf = {(_Float16)(-INFINITY), (_Float16)(-INFINITY)};
            mx0 = ninf; mx1 = ninf; mx2 = ninf; mx3 = ninf;
        }
        if (wv_ == 7) {
            for (int nt = 0; nt < 13; ++nt) {
                f32x4 macc = (f32x4){0.f, 0.f, 0.f, 0.f};
#pragma unroll
                for (int k2 = 0; k2 < 2; ++k2) {
                    int kb = k2 * 32 + q * 8;
                    f16x8v sa = *(const f16x8v*)&S16h[c * S16ST + kb];
                    f16x8v bh = *(const f16x8v*)&BHh[(nt * 16 + c) * BHST + kb];
                    macc = __builtin_amdgcn_mfma_f32_16x16x32_f16(sa, bh, macc, 0, 0, 0);
                }
                int h = nt * 16 + c;
                if (h < 200) {
#pragma unroll
                    for (int r = 0; r < 4; ++r)
                        meanLh[(q * 4 + r) * MLST + h] = (_Float16)(macc[r] * 0.125f);
                }
            }
        } else if (t < 400) {
            const _Float16* srow = &S16h[arow * S16ST];
            const _Float16* bcol = &BT16[ack * 8];
            for (int kg = 0; kg < 8; ++kg) {
                f16x8v sr = *(const f16x8v*)&srow[kg * 8];
#pragma unroll
                for (int kk = 0; kk < 8; ++kk) {
                    _Float16 sh = sr[kk];
                    f16x2 sv = {sh, sh};
                    f16x8v bv = *(const f16x8v*)&bcol[(kg * 8 + kk) * KST];
                    f16x2 p0 = sv * __builtin_shufflevector(bv, bv, 0, 1);
                    f16x2 p1 = sv * __builtin_shufflevector(bv, bv, 2, 3);
                    f16x2 p2 = sv * __builtin_shufflevector(bv, bv, 4, 5);
                    f16x2 p3 = sv * __builtin_shufflevector(bv, bv, 6, 7);
                    mx0 = __builtin_elementwise_max(mx0, p0);
                    mx1 = __builtin_elementwise_max(mx1, p1);
                    mx2 = __builtin_elementwise_max(mx2, p2);
                    mx3 = __builtin_elementwise_max(mx3, p3);
                }
            }
        }
        __syncthreads();   // B4 — meanL done; PB/WB overlays may begin

        // ---- phase 3: matches m=0 (full), m=1 (att_mean numerator), m=2 (att_max)
#pragma unroll
        for (int m = 0; m < 3; ++m) {
            if (t < 400) {
                float yv[8];
                if (m == 0) {
#pragma unroll
                    for (int i = 0; i < 8; ++i) yv[i] = yv0[i];
                } else if (m == 1) {
                    // cosine is scale-invariant; reference divisor is a positive
                    // per-row scalar, so the raw (x0.125) numerator is equivalent.
                    f16x8v yl = *(const f16x8v*)&meanLh[arow * MLST + ack * 8];
#pragma unroll
                    for (int i = 0; i < 8; ++i) yv[i] = (float)yl[i];
                } else {
                    yv[0] = (float)mx0[0]; yv[1] = (float)mx0[1];
                    yv[2] = (float)mx1[0]; yv[3] = (float)mx1[1];
                    yv[4] = (float)mx2[0]; yv[5] = (float)mx2[1];
                    yv[6] = (float)mx3[0]; yv[7] = (float)mx3[1];
                }
                f16x8v r1, r2;
#pragma unroll
                for (int i = 0; i < 8; ++i) {
                    r1[i] = (_Float16)(xr[i] * yv[i]);
                    r2[i] = (_Float16)(yv[i] * yv[i]);
                }
                if (m == 0) {
                    f16x8v r0;
#pragma unroll
                    for (int i = 0; i < 8; ++i) r0[i] = (_Float16)(xr[i] * xr[i]);
                    *(f16x8v*)&PB[(0 * 16 + arow) * KST + ack * 8] = r0;
                }
                *(f16x8v*)&PB[(1 * 16 + arow) * KST + ack * 8] = r1;
                *(f16x8v*)&PB[(2 * 16 + arow) * KST + ack * 8] = r2;
            }
            if (t < 500) {
                int wl = t / 25, wck = t % 25;
                f16x8v wr;
                if (m == 0) {
#pragma unroll
                    for (int i = 0; i < 8; ++i) wr[i] = (_Float16)(wf0[i] * wf0[i]);
                } else if (m == 1) {
#pragma unroll
                    for (int i = 0; i < 8; ++i) wr[i] = (_Float16)(wf1[i] * wf1[i]);
                } else {
#pragma unroll
                    for (int i = 0; i < 8; ++i) wr[i] = (_Float16)(wf2[i] * wf2[i]);
                }
                *(f16x8v*)&WB[wl * KST + wck * 8] = wr;
            }
            if (m == 0) {
                // one-time zeros: PB pads (144), WB rows 20-31 (336), WB rows 0-19 pads (60)
                f16x8v z8 = (f16x8v)(_Float16)0.f;
                for (int e = t; e < 540; e += 512) {
                    if (e < 144) { int row = e / 3, ckp = 25 + e % 3;
                        *(f16x8v*)&PB[row * KST + ckp * 8] = z8;
                    } else if (e < 480) { int e2 = e - 144; int row = 20 + e2 / 28, ckp = e2 % 28;
                        *(f16x8v*)&WB[row * KST + ckp * 8] = z8;
                    } else { int e2 = e - 480; int row = e2 / 3, ckp = 25 + e2 % 3;
                        *(f16x8v*)&WB[row * KST + ckp * 8] = z8;
                    }
                }
            }
            __syncthreads();

            if (wv_ < 2) {
                int ntile = wv_;
                f32x4 accA = (f32x4){0.f, 0.f, 0.f, 0.f};
                f32x4 accD = (f32x4){0.f, 0.f, 0.f, 0.f};
                f32x4 accB = (f32x4){0.f, 0.f, 0.f, 0.f};
                for (int ks = 0; ks < 7; ++ks) {
                    int kb = ks * 32 + q * 8;
                    f16x8v bfw = *(const f16x8v*)&WB[(ntile * 16 + c) * KST + kb];
                    f16x8v a0 = *(const f16x8v*)&PB[(0 * 16 + c) * KST + kb];
                    f16x8v a1 = *(const f16x8v*)&PB[(1 * 16 + c) * KST + kb];
                    f16x8v a2 = *(const f16x8v*)&PB[(2 * 16 + c) * KST + kb];
                    accA = __builtin_amdgcn_mfma_f32_16x16x32_f16(a0, bfw, accA, 0, 0, 0);
                    accD = __builtin_amdgcn_mfma_f32_16x16x32_f16(a1, bfw, accD, 0, 0, 0);
                    accB = __builtin_amdgcn_mfma_f32_16x16x32_f16(a2, bfw, accB, 0, 0, 0);
                }
                int l_ = ntile * 16 + c;
                if (l_ < LL) {
                    int chunk = (m == 0) ? 0 : (m == 1) ? 40 : 60;
#pragma unroll
                    for (int r = 0; r < 4; ++r) {
                        int s = qh * 16 + q * 4 + r;
                        float cosv = accD[r] / fmaxf(sqrtf(accA[r] * accB[r]), EPS);
                        out[side * (BB * SS * 160) + (b * SS + s) * 160 + dir * 80 + chunk + l_] = cosv;
                    }
                }
            }
            if (m < 2) __syncthreads();
        }
    } else {
        // ================================ type C: pairwise bf16 MFMA, diag norms (r7 VERBATIM)
        __hip_bfloat16* AT = (__hip_bfloat16*)smem;            // 64*KST bf16
        __hip_bfloat16* BT = (__hip_bfloat16*)(smem + 7424);   // 64*KST bf16
        float* cmL = smem + 14848;                             // 256 fl
        float* nA  = smem + 15104;                             // 64
        float* nB  = smem + 15168;                             // 64
        int blk = grp * 5 + (rem - 2);   // 0..1279
        int l = blk % LL; int db = blk / LL; int b = db & 31; int dir = db >> 5;

        const float* wrow = (dir ? w4 : w3) + l * HH;
        const float* Ag = conp + dir * HH;
        const float* Bg = conh + dir * HH;

        for (int e = t; e < 64 * 28; e += 512) {
            int m = e / 28, ck = e - m * 28;
            int k = ck * 8;
            __align__(16) __hip_bfloat16 at8[8];
            __align__(16) __hip_bfloat16 bt8[8];
            if (k < HH) {
                const float* ap = Ag + (b * SS + m) * (2 * HH) + k;
                const float* bp = Bg + (b * SS + m) * (2 * HH) + k;
                const float* wp = wrow + k;
                float av[8], bv[8], wvv[8];
                *(float4*)&av[0]  = *(const float4*)ap; *(float4*)&av[4]  = *(const float4*)(ap + 4);
                *(float4*)&bv[0]  = *(const float4*)bp; *(float4*)&bv[4]  = *(const float4*)(bp + 4);
                *(float4*)&wvv[0] = *(const float4*)wp; *(float4*)&wvv[4] = *(const float4*)(wp + 4);
#pragma unroll
                for (int i = 0; i < 8; ++i) {
                    at8[i] = __float2bfloat16(av[i] * wvv[i]);
                    bt8[i] = __float2bfloat16(bv[i] * wvv[i]);
                }
            } else {
#pragma unroll
                for (int ii = 0; ii < 8; ++ii) { at8[ii] = __float2bfloat16(0.f); bt8[ii] = __float2bfloat16(0.f); }
            }
            *(bf16x8*)&AT[m * KST + k] = *(bf16x8*)at8;
            *(bf16x8*)&BT[m * KST + k] = *(bf16x8*)bt8;
        }
        __syncthreads();   // B1

        int wv_ = __builtin_amdgcn_readfirstlane(t >> 6);
        int lane = t & 63;
        int q = lane >> 4, c = lane & 15;
        int m0 = wv_ * 16;

        f32x4 acc[4];
#pragma unroll
        for (int ct = 0; ct < 4; ++ct) acc[ct] = (f32x4){0.f, 0.f, 0.f, 0.f};

        if (wv_ < 4) {
            for (int ks = 0; ks < 7; ++ks) {
                int kb = ks * 32 + q * 8;
                bf16x8 af = *(const bf16x8*)&AT[(m0 + c) * KST + kb];
#pragma unroll
                for (int ct = 0; ct < 4; ++ct) {
                    bf16x8 bf_ = *(const bf16x8*)&BT[(ct * 16 + c) * KST + kb];
                    acc[ct] = __builtin_amdgcn_mfma_f32_16x16x32_bf16(af, bf_, acc[ct], 0, 0, 0);
                }
            }
        } else {
            int d0 = (wv_ - 4) * 16;
            f32x4 accA = (f32x4){0.f, 0.f, 0.f, 0.f};
            f32x4 accB = (f32x4){0.f, 0.f, 0.f, 0.f};
            for (int ks = 0; ks < 7; ++ks) {
                int kb = ks * 32 + q * 8;
                bf16x8 af = *(const bf16x8*)&AT[(d0 + c) * KST + kb];
                bf16x8 bf_ = *(const bf16x8*)&BT[(d0 + c) * KST + kb];
                accA = __builtin_amdgcn_mfma_f32_16x16x32_bf16(af, af, accA, 0, 0, 0);
                accB = __builtin_amdgcn_mfma_f32_16x16x32_bf16(bf_, bf_, accB, 0, 0, 0);
            }
            if ((c >> 2) == q) { nA[d0 + c] = accA[c & 3]; nB[d0 + c] = accB[c & 3]; }
        }
        __syncthreads();   // B2 — diag norms visible

        if (wv_ < 4) {
            float na[4], nb[4];
#pragma unroll
            for (int r = 0; r < 4; ++r) na[r] = sqrtf(nA[m0 + q * 4 + r]);
#pragma unroll
            for (int ct = 0; ct < 4; ++ct) nb[ct] = sqrtf(nB[ct * 16 + c]);

            float rowm[4] = {-INFINITY, -INFINITY, -INFINITY, -INFINITY};
            float colm[4] = {-INFINITY, -INFINITY, -INFINITY, -INFINITY};
#pragma unroll
            for (int ct = 0; ct < 4; ++ct) {
#pragma unroll
                for (int r = 0; r < 4; ++r) {
                    float cv = acc[ct][r] / fmaxf(na[r] * nb[ct], EPS);
                    rowm[r] = fmaxf(rowm[r], cv);
                    colm[ct] = fmaxf(colm[ct], cv);
                }
            }

#pragma unroll
            for (int r = 0; r < 4; ++r) {
                float v = rowm[r];
                v = fmaxf(v, __shfl_xor(v, 1, 64));
                v = fmaxf(v, __shfl_xor(v, 2, 64));
                v = fmaxf(v, __shfl_xor(v, 4, 64));
                v = fmaxf(v, __shfl_xor(v, 8, 64));
                rowm[r] = v;
            }
            if (c == 0) {
#pragma unroll
                for (int r = 0; r < 4; ++r) {
                    int i = m0 + q * 4 + r;
                    out[(b * SS + i) * 160 + dir * 80 + 20 + l] = rowm[r];
                }
            }

#pragma unroll
            for (int ct = 0; ct < 4; ++ct) {
                float v = colm[ct];
                v = fmaxf(v, __shfl_xor(v, 16, 64));
                v = fmaxf(v, __shfl_xor(v, 32, 64));
                colm[ct] = v;
            }
            if (q == 0) {
#pragma unroll
                for (int ct = 0; ct < 4; ++ct) cmL[wv_ * 64 + ct * 16 + c] = colm[ct];
            }
        }
        __syncthreads();   // B3
        if (t < 64) {
            float m = fmaxf(fmaxf(cmL[t], cmL[64 + t]), fmaxf(cmL[128 + t], cmL[192 + t]));
            out[BB * SS * 160 + (b * SS + t) * 160 + dir * 80 + 20 + l] = m;
        }
    }
}

extern "C" void kernel_launch(void* const* d_in, const int* in_sizes, int n_in,
                              void* d_out, int out_size, void* d_ws, size_t ws_size,
                              hipStream_t stream) {
    const float* conp = (const float*)d_in[0];
    const float* conh = (const float*)d_in[1];
    const float* w1 = (const float*)d_in[2];
    const float* w2 = (const float*)d_in[3];
    const float* w3 = (const float*)d_in[4];
    const float* w4 = (const float*)d_in[5];
    const float* w5 = (const float*)d_in[6];
    const float* w6 = (const float*)d_in[7];
    const float* w7 = (const float*)d_in[8];
    const float* w8 = (const float*)d_in[9];
    float* out = (float*)d_out;
    (void)d_ws; (void)ws_size;

    fused_all_kernel<<<1792, 512, 0, stream>>>(conp, conh,
                                               w1, w2, w3, w4, w5, w6, w7, w8, out);
}

// Round 10
// 101.738 us; speedup vs baseline: 1.1676x; 1.0558x over previous
//
#include <hip/hip_runtime.h>
#include <hip/hip_bf16.h>
#include <math.h>

#define EPS 1e-8f
#define BB 32
#define SS 64
#define HH 200
#define LL 20
#define KST 232   // f16 LDS row stride (464B -> 2-way bank walk)
#define S16ST 72  // S16 row stride (f16)
#define BHST 72   // BH row stride (f16)
#define MLST 208  // meanL row stride (f16)

typedef short bf16x8 __attribute__((ext_vector_type(8)));
typedef float f32x4 __attribute__((ext_vector_type(4)));
typedef _Float16 f16x8v __attribute__((ext_vector_type(8)));
typedef _Float16 f16x2 __attribute__((ext_vector_type(2)));

// ONE kernel, grid 768 x 512 (256 groups of 3: 2 type-A + 1 type-C). No workspace.
// r10 = r9 type-A VERBATIM + type-C collapsed 5x: one C block = (dir,b,lg) covers
// l = lg*5..lg*5+4 from ONE raw-f16 staging. w^2 folded onto the A operand
// (dot = sum a*b*w^2), so B fragments/staging are shared across l. Norms via
// diag(mfma(a*w^2, a_raw)) on waves 4-7 for all 5 l. 3 barriers.
//
// Type A LDS (floats, 19104 = 76.4 KB -> 2 blocks/CU): as r9.
// Type C LDS (floats, 17352): ATr 64xKST f16 [0,7424) | BTr [7424,14848) |
//   w2L 5xKST f16 [14848,15428) | nA5 5x64 [15432,15752) | nB5 [15752,16072) |
//   cmL5 5x256 [16072,17352)
__global__ __launch_bounds__(512, 4) void fused_all_kernel(
        const float* __restrict__ conp, const float* __restrict__ conh,
        const float* __restrict__ w1, const float* __restrict__ w2,
        const float* __restrict__ w3, const float* __restrict__ w4,
        const float* __restrict__ w5, const float* __restrict__ w6,
        const float* __restrict__ w7, const float* __restrict__ w8,
        float* __restrict__ out) {
    __shared__ __align__(16) float smem[19104];
    int t = threadIdx.x;

    // XCD-aware swizzle (bijective on [0,768) = 8 x 96)
    int wg = ((blockIdx.x & 7) * 96) + (blockIdx.x >> 3);
    int grp = wg / 3;
    int rem = wg % 3;

    if (rem < 2) {
        // ================================ type A (16 self-rows, f16) — r9 VERBATIM
        _Float16* AT16 = (_Float16*)smem;
        _Float16* BT16 = (_Float16*)(smem + 1856);
        _Float16* BHh  = (_Float16*)(smem + 9280);
        _Float16* S16h = (_Float16*)(smem + 16768);
        float* nrmA  = smem + 17344;
        float* nrmB  = smem + 17360;
        _Float16* meanLh = (_Float16*)(smem + 17440);
        _Float16* PB = (_Float16*)smem;            // phase 3: 48xKST
        _Float16* WB = (_Float16*)(smem + 5568);   // phase 3: 32xKST

        int blk = grp * 2 + rem;       // 0..511
        int qh = blk & 3;              // 16-row quarter of self side
        int sdb = blk >> 2;
        int b = sdb & 31, sd = sdb >> 5;
        int dir = sd & 1, side = sd >> 1;
        const float* selfb = side ? conh : conp;
        const float* oppb  = side ? conp : conh;
        int fidx = dir ? 0 : (SS - 1);
        const float* fvr = oppb + (b * SS + fidx) * (2 * HH) + dir * HH;

        int arow = t / 25, ack = t % 25;

        float xr[8], yv0[8];
        if (t < 400) {
            const float* xp = selfb + (b * SS + qh * 16 + arow) * (2 * HH) + dir * HH + ack * 8;
            *(float4*)&xr[0] = *(const float4*)xp; *(float4*)&xr[4] = *(const float4*)(xp + 4);
            *(float4*)&yv0[0] = *(const float4*)(fvr + ack * 8);
            *(float4*)&yv0[4] = *(const float4*)(fvr + ack * 8 + 4);
            f16x8v r8;
#pragma unroll
            for (int i = 0; i < 8; ++i) r8[i] = (_Float16)xr[i];
            *(f16x8v*)&AT16[arow * KST + ack * 8] = r8;
        }
        {
            f16x8v z8 = (f16x8v)(_Float16)0.f;
            if (t < 312) {
                if (t < 48) { int row = t / 3, ckp = 25 + t % 3;
                    *(f16x8v*)&AT16[row * KST + ckp * 8] = z8;
                } else if (t < 240) { int e2 = t - 48; int row = e2 / 3, ckp = 25 + e2 % 3;
                    *(f16x8v*)&BT16[row * KST + ckp * 8] = z8;
                } else { int e2 = t - 240; int row = 200 + e2 / 9, c8 = (e2 % 9) * 8;
                    *(f16x8v*)&BHh[row * BHST + c8] = z8;
                }
            }
        }
        for (int e = t; e < 1600; e += 512) {
            int rw = e / 25, ck = e % 25, k = ck * 8;
            const float* xp = oppb + (b * SS + rw) * (2 * HH) + dir * HH + k;
            float xv[8];
            *(float4*)&xv[0] = *(const float4*)xp; *(float4*)&xv[4] = *(const float4*)(xp + 4);
            f16x8v r8;
#pragma unroll
            for (int i = 0; i < 8; ++i) r8[i] = (_Float16)xv[i];
            *(f16x8v*)&BT16[rw * KST + k] = r8;
        }
        __syncthreads();   // B1

        int wv_ = __builtin_amdgcn_readfirstlane(t >> 6);
        int lane = t & 63;
        int q = lane >> 4, c = lane & 15;

        f32x4 accS = (f32x4){0.f, 0.f, 0.f, 0.f};
        if (wv_ < 4) {
            int ct = wv_;
            for (int ks = 0; ks < 7; ++ks) {
                int kb = ks * 32 + q * 8;
                f16x8v af  = *(const f16x8v*)&AT16[c * KST + kb];
                f16x8v bf_ = *(const f16x8v*)&BT16[(ct * 16 + c) * KST + kb];
                accS = __builtin_amdgcn_mfma_f32_16x16x32_f16(af, bf_, accS, 0, 0, 0);
            }
        } else {
            int dt = wv_ - 4;
            f32x4 accB = (f32x4){0.f, 0.f, 0.f, 0.f};
            for (int ks = 0; ks < 7; ++ks) {
                int kb = ks * 32 + q * 8;
                f16x8v bf_ = *(const f16x8v*)&BT16[(dt * 16 + c) * KST + kb];
                accB = __builtin_amdgcn_mfma_f32_16x16x32_f16(bf_, bf_, accB, 0, 0, 0);
            }
            if ((c >> 2) == q) nrmB[dt * 16 + c] = accB[c & 3];
            if (dt == 0) {
                f32x4 accA = (f32x4){0.f, 0.f, 0.f, 0.f};
                for (int ks = 0; ks < 7; ++ks) {
                    int kb = ks * 32 + q * 8;
                    f16x8v af = *(const f16x8v*)&AT16[c * KST + kb];
                    accA = __builtin_amdgcn_mfma_f32_16x16x32_f16(af, af, accA, 0, 0, 0);
                }
                if ((c >> 2) == q) nrmA[c] = accA[c & 3];
            } else {
                for (int ch = dt - 1; ch < 25; ch += 3) {
                    f16x8v v = *(const f16x8v*)&BT16[lane * KST + ch * 8];
#pragma unroll
                    for (int i = 0; i < 8; ++i) BHh[(ch * 8 + i) * BHST + lane] = v[i];
                }
            }
        }
        __syncthreads();   // B2

        if (wv_ < 4) {
            int col = wv_ * 16 + c;
            float no = sqrtf(nrmB[col]);
#pragma unroll
            for (int r = 0; r < 4; ++r) {
                int row = q * 4 + r;
                float ns = sqrtf(nrmA[row]);
                S16h[row * S16ST + col] = (_Float16)(accS[r] / fmaxf(ns * no, EPS));
            }
        }
        __syncthreads();   // B3

        float wf0[8], wf1[8], wf2[8];
        if (t < 500) {
            int wl = t / 25, wck = t % 25;
            const float* wp0 = (dir ? w2 : w1) + wl * HH + wck * 8;
            const float* wp1 = (dir ? w6 : w5) + wl * HH + wck * 8;
            const float* wp2 = (dir ? w8 : w7) + wl * HH + wck * 8;
            *(float4*)&wf0[0] = *(const float4*)wp0; *(float4*)&wf0[4] = *(const float4*)(wp0 + 4);
            *(float4*)&wf1[0] = *(const float4*)wp1; *(float4*)&wf1[4] = *(const float4*)(wp1 + 4);
            *(float4*)&wf2[0] = *(const float4*)wp2; *(float4*)&wf2[4] = *(const float4*)(wp2 + 4);
        }

        f16x2 mx0, mx1, mx2, mx3;
        {
            f16x2 ninf = {(_Float16)(-INFINITY), (_Float16)(-INFINITY)};
            mx0 = ninf; mx1 = ninf; mx2 = ninf; mx3 = ninf;
        }
        if (wv_ == 7) {
            for (int nt = 0; nt < 13; ++nt) {
                f32x4 macc = (f32x4){0.f, 0.f, 0.f, 0.f};
#pragma unroll
                for (int k2 = 0; k2 < 2; ++k2) {
                    int kb = k2 * 32 + q * 8;
                    f16x8v sa = *(const f16x8v*)&S16h[c * S16ST + kb];
                    f16x8v bh = *(const f16x8v*)&BHh[(nt * 16 + c) * BHST + kb];
                    macc = __builtin_amdgcn_mfma_f32_16x16x32_f16(sa, bh, macc, 0, 0, 0);
                }
                int h = nt * 16 + c;
                if (h < 200) {
#pragma unroll
                    for (int r = 0; r < 4; ++r)
                        meanLh[(q * 4 + r) * MLST + h] = (_Float16)(macc[r] * 0.125f);
                }
            }
        } else if (t < 400) {
            const _Float16* srow = &S16h[arow * S16ST];
            const _Float16* bcol = &BT16[ack * 8];
            for (int kg = 0; kg < 8; ++kg) {
                f16x8v sr = *(const f16x8v*)&srow[kg * 8];
#pragma unroll
                for (int kk = 0; kk < 8; ++kk) {
                    _Float16 sh = sr[kk];
                    f16x2 sv = {sh, sh};
                    f16x8v bv = *(const f16x8v*)&bcol[(kg * 8 + kk) * KST];
                    f16x2 p0 = sv * __builtin_shufflevector(bv, bv, 0, 1);
                    f16x2 p1 = sv * __builtin_shufflevector(bv, bv, 2, 3);
                    f16x2 p2 = sv * __builtin_shufflevector(bv, bv, 4, 5);
                    f16x2 p3 = sv * __builtin_shufflevector(bv, bv, 6, 7);
                    mx0 = __builtin_elementwise_max(mx0, p0);
                    mx1 = __builtin_elementwise_max(mx1, p1);
                    mx2 = __builtin_elementwise_max(mx2, p2);
                    mx3 = __builtin_elementwise_max(mx3, p3);
                }
            }
        }
        __syncthreads();   // B4

#pragma unroll
        for (int m = 0; m < 3; ++m) {
            if (t < 400) {
                float yv[8];
                if (m == 0) {
#pragma unroll
                    for (int i = 0; i < 8; ++i) yv[i] = yv0[i];
                } else if (m == 1) {
                    f16x8v yl = *(const f16x8v*)&meanLh[arow * MLST + ack * 8];
#pragma unroll
                    for (int i = 0; i < 8; ++i) yv[i] = (float)yl[i];
                } else {
                    yv[0] = (float)mx0[0]; yv[1] = (float)mx0[1];
                    yv[2] = (float)mx1[0]; yv[3] = (float)mx1[1];
                    yv[4] = (float)mx2[0]; yv[5] = (float)mx2[1];
                    yv[6] = (float)mx3[0]; yv[7] = (float)mx3[1];
                }
                f16x8v r1, r2;
#pragma unroll
                for (int i = 0; i < 8; ++i) {
                    r1[i] = (_Float16)(xr[i] * yv[i]);
                    r2[i] = (_Float16)(yv[i] * yv[i]);
                }
                if (m == 0) {
                    f16x8v r0;
#pragma unroll
                    for (int i = 0; i < 8; ++i) r0[i] = (_Float16)(xr[i] * xr[i]);
                    *(f16x8v*)&PB[(0 * 16 + arow) * KST + ack * 8] = r0;
                }
                *(f16x8v*)&PB[(1 * 16 + arow) * KST + ack * 8] = r1;
                *(f16x8v*)&PB[(2 * 16 + arow) * KST + ack * 8] = r2;
            }
            if (t < 500) {
                int wl = t / 25, wck = t % 25;
                f16x8v wr;
                if (m == 0) {
#pragma unroll
                    for (int i = 0; i < 8; ++i) wr[i] = (_Float16)(wf0[i] * wf0[i]);
                } else if (m == 1) {
#pragma unroll
                    for (int i = 0; i < 8; ++i) wr[i] = (_Float16)(wf1[i] * wf1[i]);
                } else {
#pragma unroll
                    for (int i = 0; i < 8; ++i) wr[i] = (_Float16)(wf2[i] * wf2[i]);
                }
                *(f16x8v*)&WB[wl * KST + wck * 8] = wr;
            }
            if (m == 0) {
                f16x8v z8 = (f16x8v)(_Float16)0.f;
                for (int e = t; e < 540; e += 512) {
                    if (e < 144) { int row = e / 3, ckp = 25 + e % 3;
                        *(f16x8v*)&PB[row * KST + ckp * 8] = z8;
                    } else if (e < 480) { int e2 = e - 144; int row = 20 + e2 / 28, ckp = e2 % 28;
                        *(f16x8v*)&WB[row * KST + ckp * 8] = z8;
                    } else { int e2 = e - 480; int row = e2 / 3, ckp = 25 + e2 % 3;
                        *(f16x8v*)&WB[row * KST + ckp * 8] = z8;
                    }
                }
            }
            __syncthreads();

            if (wv_ < 2) {
                int ntile = wv_;
                f32x4 accA = (f32x4){0.f, 0.f, 0.f, 0.f};
                f32x4 accD = (f32x4){0.f, 0.f, 0.f, 0.f};
                f32x4 accB = (f32x4){0.f, 0.f, 0.f, 0.f};
                for (int ks = 0; ks < 7; ++ks) {
                    int kb = ks * 32 + q * 8;
                    f16x8v bfw = *(const f16x8v*)&WB[(ntile * 16 + c) * KST + kb];
                    f16x8v a0 = *(const f16x8v*)&PB[(0 * 16 + c) * KST + kb];
                    f16x8v a1 = *(const f16x8v*)&PB[(1 * 16 + c) * KST + kb];
                    f16x8v a2 = *(const f16x8v*)&PB[(2 * 16 + c) * KST + kb];
                    accA = __builtin_amdgcn_mfma_f32_16x16x32_f16(a0, bfw, accA, 0, 0, 0);
                    accD = __builtin_amdgcn_mfma_f32_16x16x32_f16(a1, bfw, accD, 0, 0, 0);
                    accB = __builtin_amdgcn_mfma_f32_16x16x32_f16(a2, bfw, accB, 0, 0, 0);
                }
                int l_ = ntile * 16 + c;
                if (l_ < LL) {
                    int chunk = (m == 0) ? 0 : (m == 1) ? 40 : 60;
#pragma unroll
                    for (int r = 0; r < 4; ++r) {
                        int s = qh * 16 + q * 4 + r;
                        float cosv = accD[r] / fmaxf(sqrtf(accA[r] * accB[r]), EPS);
                        out[side * (BB * SS * 160) + (b * SS + s) * 160 + dir * 80 + chunk + l_] = cosv;
                    }
                }
            }
            if (m < 2) __syncthreads();
        }
    } else {
        // ================================ type C: 5-l pairwise, f16, w^2-on-A
        _Float16* ATr = (_Float16*)smem;             // 64xKST raw A (f16)
        _Float16* BTr = (_Float16*)(smem + 7424);    // 64xKST raw B (f16)
        _Float16* w2L = (_Float16*)(smem + 14848);   // 5xKST w^2 (f16)
        float* nA5  = smem + 15432;                  // 5x64
        float* nB5  = smem + 15752;                  // 5x64
        float* cmL5 = smem + 16072;                  // 5x256

        int cblk = grp;              // 0..255
        int lg = cblk & 3;
        int db = cblk >> 2;          // 0..63
        int b = db & 31, dir = db >> 5;
        int l0 = lg * 5;
        const float* wsrc = dir ? w4 : w3;
        const float* Ag = conp + dir * HH;
        const float* Bg = conh + dir * HH;

        // ---- staging: raw rows (f16), 3200 items; pads; w^2 rows
        for (int e = t; e < 3200; e += 512) {
            int half = (e >= 1600) ? 1 : 0;
            int e2 = e - half * 1600;
            int rw = e2 / 25, ck = e2 % 25, k = ck * 8;
            const float* xp = (half ? Bg : Ag) + (b * SS + rw) * (2 * HH) + k;
            float xv[8];
            *(float4*)&xv[0] = *(const float4*)xp; *(float4*)&xv[4] = *(const float4*)(xp + 4);
            f16x8v r8;
#pragma unroll
            for (int i = 0; i < 8; ++i) r8[i] = (_Float16)xv[i];
            _Float16* dst = half ? BTr : ATr;
            *(f16x8v*)&dst[rw * KST + k] = r8;
        }
        {
            f16x8v z8 = (f16x8v)(_Float16)0.f;
            if (t < 384) {
                int half = (t >= 192) ? 1 : 0;
                int e2 = t - half * 192;
                int row = e2 / 3, ckp = 25 + e2 % 3;
                _Float16* dst = half ? BTr : ATr;
                *(f16x8v*)&dst[row * KST + ckp * 8] = z8;
            } else if (t < 399) {
                int e2 = t - 384;
                int wl = e2 / 3, ckp = 25 + e2 % 3;
                *(f16x8v*)&w2L[wl * KST + ckp * 8] = z8;
            }
            if (t < 125) {
                int wl = t / 25, wck = t % 25;
                const float* wp = wsrc + (l0 + wl) * HH + wck * 8;
                float wvv[8];
                *(float4*)&wvv[0] = *(const float4*)wp; *(float4*)&wvv[4] = *(const float4*)(wp + 4);
                f16x8v r8;
#pragma unroll
                for (int i = 0; i < 8; ++i) r8[i] = (_Float16)(wvv[i] * wvv[i]);
                *(f16x8v*)&w2L[wl * KST + wck * 8] = r8;
            }
        }
        __syncthreads();   // B1

        int wv_ = __builtin_amdgcn_readfirstlane(t >> 6);
        int lane = t & 63;
        int q = lane >> 4, c = lane & 15;
        int m0 = (wv_ & 3) * 16;

        f32x4 z4 = (f32x4){0.f, 0.f, 0.f, 0.f};
        f32x4 acc0[4] = {z4, z4, z4, z4};
        f32x4 acc1[4] = {z4, z4, z4, z4};
        f32x4 acc2[4] = {z4, z4, z4, z4};

        if (wv_ < 4) {
            // ---- pass 1: li = 0,1,2 (acc held across B2)
            for (int ks = 0; ks < 7; ++ks) {
                int kb = ks * 32 + q * 8;
                f16x8v ar  = *(const f16x8v*)&ATr[(m0 + c) * KST + kb];
                f16x8v ww0 = *(const f16x8v*)&w2L[0 * KST + kb];
                f16x8v ww1 = *(const f16x8v*)&w2L[1 * KST + kb];
                f16x8v ww2 = *(const f16x8v*)&w2L[2 * KST + kb];
                f16x8v af0 = ar * ww0, af1 = ar * ww1, af2 = ar * ww2;
#pragma unroll
                for (int ct = 0; ct < 4; ++ct) {
                    f16x8v br = *(const f16x8v*)&BTr[(ct * 16 + c) * KST + kb];
                    acc0[ct] = __builtin_amdgcn_mfma_f32_16x16x32_f16(af0, br, acc0[ct], 0, 0, 0);
                    acc1[ct] = __builtin_amdgcn_mfma_f32_16x16x32_f16(af1, br, acc1[ct], 0, 0, 0);
                    acc2[ct] = __builtin_amdgcn_mfma_f32_16x16x32_f16(af2, br, acc2[ct], 0, 0, 0);
                }
            }
        } else {
            // ---- waves 4-7: norms for 16 rows each, all 5 li
            int d0 = (wv_ - 4) * 16;
            f32x4 nacA[5] = {z4, z4, z4, z4, z4};
            f32x4 nacB[5] = {z4, z4, z4, z4, z4};
            for (int ks = 0; ks < 7; ++ks) {
                int kb = ks * 32 + q * 8;
                f16x8v ar = *(const f16x8v*)&ATr[(d0 + c) * KST + kb];
                f16x8v br = *(const f16x8v*)&BTr[(d0 + c) * KST + kb];
#pragma unroll
                for (int li = 0; li < 5; ++li) {
                    f16x8v wf = *(const f16x8v*)&w2L[li * KST + kb];
                    f16x8v afw = ar * wf;
                    f16x8v bfw = br * wf;
                    nacA[li] = __builtin_amdgcn_mfma_f32_16x16x32_f16(afw, ar, nacA[li], 0, 0, 0);
                    nacB[li] = __builtin_amdgcn_mfma_f32_16x16x32_f16(bfw, br, nacB[li], 0, 0, 0);
                }
            }
            if ((c >> 2) == q) {
#pragma unroll
                for (int li = 0; li < 5; ++li) {
                    nA5[li * 64 + d0 + c] = nacA[li][c & 3];
                    nB5[li * 64 + d0 + c] = nacB[li][c & 3];
                }
            }
        }
        __syncthreads();   // B2 — norms visible

#define C_EPI(LI, ACC) do { \
    float na_[4], nb_[4]; \
    _Pragma("unroll") for (int r_ = 0; r_ < 4; ++r_) na_[r_] = sqrtf(nA5[(LI) * 64 + m0 + q * 4 + r_]); \
    _Pragma("unroll") for (int ct_ = 0; ct_ < 4; ++ct_) nb_[ct_] = sqrtf(nB5[(LI) * 64 + ct_ * 16 + c]); \
    float rowm_[4] = {-INFINITY, -INFINITY, -INFINITY, -INFINITY}; \
    float colm_[4] = {-INFINITY, -INFINITY, -INFINITY, -INFINITY}; \
    _Pragma("unroll") for (int ct_ = 0; ct_ < 4; ++ct_) { \
        _Pragma("unroll") for (int r_ = 0; r_ < 4; ++r_) { \
            float cv_ = (ACC)[ct_][r_] / fmaxf(na_[r_] * nb_[ct_], EPS); \
            rowm_[r_] = fmaxf(rowm_[r_], cv_); \
            colm_[ct_] = fmaxf(colm_[ct_], cv_); \
        } \
    } \
    _Pragma("unroll") for (int r_ = 0; r_ < 4; ++r_) { \
        float v_ = rowm_[r_]; \
        v_ = fmaxf(v_, __shfl_xor(v_, 1, 64)); \
        v_ = fmaxf(v_, __shfl_xor(v_, 2, 64)); \
        v_ = fmaxf(v_, __shfl_xor(v_, 4, 64)); \
        v_ = fmaxf(v_, __shfl_xor(v_, 8, 64)); \
        rowm_[r_] = v_; \
    } \
    if (c == 0) { \
        _Pragma("unroll") for (int r_ = 0; r_ < 4; ++r_) \
            out[(b * SS + m0 + q * 4 + r_) * 160 + dir * 80 + 20 + l0 + (LI)] = rowm_[r_]; \
    } \
    _Pragma("unroll") for (int ct_ = 0; ct_ < 4; ++ct_) { \
        float v_ = colm_[ct_]; \
        v_ = fmaxf(v_, __shfl_xor(v_, 16, 64)); \
        v_ = fmaxf(v_, __shfl_xor(v_, 32, 64)); \
        colm_[ct_] = v_; \
    } \
    if (q == 0) { \
        _Pragma("unroll") for (int ct_ = 0; ct_ < 4; ++ct_) \
            cmL5[(LI) * 256 + wv_ * 64 + ct_ * 16 + c] = colm_[ct_]; \
    } \
} while (0)

        if (wv_ < 4) {
            C_EPI(0, acc0);
            C_EPI(1, acc1);
            C_EPI(2, acc2);
            // ---- pass 2: li = 3,4 (reuse acc0/acc1 registers)
            f32x4 acc3[4] = {z4, z4, z4, z4};
            f32x4 acc4[4] = {z4, z4, z4, z4};
            for (int ks = 0; ks < 7; ++ks) {
                int kb = ks * 32 + q * 8;
                f16x8v ar  = *(const f16x8v*)&ATr[(m0 + c) * KST + kb];
                f16x8v ww3 = *(const f16x8v*)&w2L[3 * KST + kb];
                f16x8v ww4 = *(const f16x8v*)&w2L[4 * KST + kb];
                f16x8v af3 = ar * ww3, af4 = ar * ww4;
#pragma unroll
                for (int ct = 0; ct < 4; ++ct) {
                    f16x8v br = *(const f16x8v*)&BTr[(ct * 16 + c) * KST + kb];
                    acc3[ct] = __builtin_amdgcn_mfma_f32_16x16x32_f16(af3, br, acc3[ct], 0, 0, 0);
                    acc4[ct] = __builtin_amdgcn_mfma_f32_16x16x32_f16(af4, br, acc4[ct], 0, 0, 0);
                }
            }
            C_EPI(3, acc3);
            C_EPI(4, acc4);
        }
        __syncthreads();   // B3 — cmL5 complete

        if (t < 320) {
            int li = t >> 6, j = t & 63;
            const float* cm = &cmL5[li * 256];
            float mm = fmaxf(fmaxf(cm[j], cm[64 + j]), fmaxf(cm[128 + j], cm[192 + j]));
            out[BB * SS * 160 + (b * SS + j) * 160 + dir * 80 + 20 + l0 + li] = mm;
        }
#undef C_EPI
    }
}

extern "C" void kernel_launch(void* const* d_in, const int* in_sizes, int n_in,
                              void* d_out, int out_size, void* d_ws, size_t ws_size,
                              hipStream_t stream) {
    const float* conp = (const float*)d_in[0];
    const float* conh = (const float*)d_in[1];
    const float* w1 = (const float*)d_in[2];
    const float* w2 = (const float*)d_in[3];
    const float* w3 = (const float*)d_in[4];
    const float* w4 = (const float*)d_in[5];
    const float* w5 = (const float*)d_in[6];
    const float* w6 = (const float*)d_in[7];
    const float* w7 = (const float*)d_in[8];
    const float* w8 = (const float*)d_in[9];
    float* out = (float*)d_out;
    (void)d_ws; (void)ws_size;

    fused_all_kernel<<<768, 512, 0, stream>>>(conp, conh,
                                              w1, w2, w3, w4, w5, w6, w7, w8, out);
}